// Round 3
// baseline (14954.152 us; speedup 1.0000x reference)
//
#include <hip/hip_runtime.h>
#include <hip/hip_bf16.h>

// ---------------- problem constants ----------------
#define B_    64
#define S_    256
#define IN_   400
#define H_    1024
#define G4_   4096          // 4*H
#define NS_   150
#define NR_   50
#define KX_   416           // IN padded to mult of 32
#define KTOT_ 1440          // H + KX = 45*32
#define NBLK_ 128
#define NTHR_ 512

typedef __attribute__((ext_vector_type(4))) float  f32x4;
typedef __attribute__((ext_vector_type(8))) __bf16 bf16x8;
typedef __attribute__((ext_vector_type(4))) __bf16 bf16x4;

#define MF(a,b,c) __builtin_amdgcn_mfma_f32_16x16x32_bf16((a),(b),(c),0,0,0)

struct Params {
  const float* WaFb; const float* WaRb;
  const float* Fw; const float* Fb; const float* Rw; const float* Rb;
  const __bf16* Wc;     // [2][4096][1440]
  const float*  bias;   // [2][4096]  (bih+bhh)
  const __bf16* Xhi;    // [256][64][416]
  const __bf16* Xlo;
  const __bf16* Wa16;   // [200][1024]
  __bf16* Thi; __bf16* Tlo;       // [64][1024]
  float* hF; float* hR;           // [64][1024]
  float* out; float* aFo; float* aRo;
  unsigned* cnt;
};

__device__ __forceinline__ float sigm(float v){ return 1.f/(1.f+expf(-v)); }

// Grid barrier with bounded spin (diagnostic hedge: a co-residency deadlock
// becomes "wrong answer", not a hung container). 1M ticks @100MHz = ~10ms,
// ~100-1000x the expected wait; normal path never hits the bound.
__device__ __forceinline__ void gbar(unsigned* cnt, unsigned target){
  __syncthreads();
  if (threadIdx.x == 0){
    __threadfence();
    atomicAdd(cnt, 1u);
    unsigned long long t0 = __builtin_amdgcn_s_memrealtime();
    while (__hip_atomic_load(cnt, __ATOMIC_RELAXED, __HIP_MEMORY_SCOPE_AGENT) < target){
      __builtin_amdgcn_s_sleep(2);
      if (__builtin_amdgcn_s_memrealtime() - t0 > 1000000ull) break;
    }
    __threadfence();
  }
  __syncthreads();
}

// ---------------- prep kernels ----------------
__global__ void prepW(const float* __restrict__ WihF, const float* __restrict__ WhhF,
                      const float* __restrict__ bihF, const float* __restrict__ bhhF,
                      const float* __restrict__ WihR, const float* __restrict__ WhhR,
                      const float* __restrict__ bihR, const float* __restrict__ bhhR,
                      const float* __restrict__ WaFw, const float* __restrict__ WaRw,
                      __bf16* __restrict__ Wc, float* __restrict__ bias,
                      __bf16* __restrict__ Wa16){
  const int row = blockIdx.x;
  if (row < 2*G4_){
    const int cell = row >> 12, n = row & 4095;
    const float* Wih = cell ? WihR : WihF;
    const float* Whh = cell ? WhhR : WhhF;
    __bf16* dst = Wc + (size_t)row * KTOT_;
    for (int k = threadIdx.x; k < KTOT_; k += 256){
      float v;
      if (k < H_)            v = Whh[(size_t)n*H_ + k];
      else if (k < H_+IN_)   v = Wih[(size_t)n*IN_ + (k - H_)];
      else                   v = 0.f;
      dst[k] = (__bf16)v;
    }
    if (threadIdx.x == 0){
      const float* bi = cell ? bihR : bihF;
      const float* bh = cell ? bhhR : bhhF;
      bias[row] = bi[n] + bh[n];
    }
  } else {
    const int r = row - 2*G4_;                 // 0..199
    const float* src = (r < NS_) ? (WaFw + (size_t)r*H_) : (WaRw + (size_t)(r-NS_)*H_);
    __bf16* dst = Wa16 + (size_t)r*H_;
    for (int k = threadIdx.x; k < H_; k += 256) dst[k] = (__bf16)src[k];
  }
}

__global__ void prepX(const float* __restrict__ x, __bf16* __restrict__ Xhi, __bf16* __restrict__ Xlo){
  const int bi = blockIdx.x;            // t*64 + b
  const int t = bi >> 6, b = bi & 63;
  const float* xr = x + ((size_t)b*S_ + t)*IN_;
  __bf16* dh = Xhi + (size_t)bi*KX_;
  __bf16* dl = Xlo + (size_t)bi*KX_;
  for (int j = threadIdx.x; j < KX_; j += 64){
    float v = (j < IN_) ? xr[j] : 0.f;
    __bf16 h = (__bf16)v;
    dh[j] = h;
    dl[j] = (__bf16)(v - (float)h);
  }
}

__global__ void prepZ(unsigned* __restrict__ Thi32, unsigned* __restrict__ Tlo32, unsigned* __restrict__ cnt){
  int i = blockIdx.x*256 + threadIdx.x;
  if (i < 32768){ Thi32[i] = 0u; Tlo32[i] = 0u; }
  if (i == 0) *cnt = 0u;
}

// ---------------- main persistent kernel ----------------
__global__ __launch_bounds__(NTHR_) void tpr_main(Params p){
  const int tid = threadIdx.x;
  const int blk = blockIdx.x;
  const int w   = tid >> 6;        // wave 0..7
  const int l   = tid & 63;
  const int l15 = l & 15;
  const int lg  = l >> 4;
  const int wm  = w & 3;           // m-tile (16 batch rows)
  const int kh  = w >> 2;          // K-half

  const int cell = blk >> 6;       // 0=F 1=R
  const int h0   = (blk & 63) << 4;

  __shared__ float shF[H_];
  __shared__ float shR[H_];
  __shared__ float ssc[NS_+NR_];
  __shared__ float sa [NS_+NR_];
  __shared__ float sitp[256];
  __shared__ float sit[64];
  __shared__ f32x4 sred[4][4][64];  // [wm][strip][lane]

  // c-state lives in registers of kh==0 waves for all 256 steps
  float cr4[4] = {0.f,0.f,0.f,0.f};

  const int koffl = lg << 3;                 // lane k-offset (elems)
  const int arow  = (wm << 4) + l15;         // A row = batch

  const __bf16* __restrict__ AhT = p.Thi + arow*H_ + koffl;
  const __bf16* __restrict__ AlT = p.Tlo + arow*H_ + koffl;

  const int nb = (cell << 12) + h0 + l15;    // gate row base (strip 0)
  const __bf16* __restrict__ Wr0 = p.Wc + (size_t)(nb          )*KTOT_ + koffl;
  const __bf16* __restrict__ Wr1 = p.Wc + (size_t)(nb + 1*H_   )*KTOT_ + koffl;
  const __bf16* __restrict__ Wr2 = p.Wc + (size_t)(nb + 2*H_   )*KTOT_ + koffl;
  const __bf16* __restrict__ Wr3 = p.Wc + (size_t)(nb + 3*H_   )*KTOT_ + koffl;
  const float b0 = p.bias[nb], b1 = p.bias[nb+1*H_], b2 = p.bias[nb+2*H_], b3 = p.bias[nb+3*H_];

  unsigned bar_t = 0;

  for (int t = 0; t < S_; ++t){
    // ================= phase A: gates GEMM + fused LSTM pointwise =================
    f32x4 acc0, acc1, acc2, acc3;
    if (kh == 0){ acc0 = {b0,b0,b0,b0}; acc1 = {b1,b1,b1,b1}; acc2 = {b2,b2,b2,b2}; acc3 = {b3,b3,b3,b3}; }
    else        { acc0 = {0,0,0,0};     acc1 = {0,0,0,0};     acc2 = {0,0,0,0};     acc3 = {0,0,0,0};     }

#define TITER(kk) { \
      bf16x8 ah = *(const bf16x8*)(AhT + ((kk)<<5)); \
      bf16x8 al = *(const bf16x8*)(AlT + ((kk)<<5)); \
      bf16x8 q0 = *(const bf16x8*)(Wr0 + ((kk)<<5)); \
      bf16x8 q1 = *(const bf16x8*)(Wr1 + ((kk)<<5)); \
      bf16x8 q2 = *(const bf16x8*)(Wr2 + ((kk)<<5)); \
      bf16x8 q3 = *(const bf16x8*)(Wr3 + ((kk)<<5)); \
      acc0 = MF(ah,q0,acc0); acc0 = MF(al,q0,acc0); \
      acc1 = MF(ah,q1,acc1); acc1 = MF(al,q1,acc1); \
      acc2 = MF(ah,q2,acc2); acc2 = MF(al,q2,acc2); \
      acc3 = MF(ah,q3,acc3); acc3 = MF(al,q3,acc3); }

    if (kh == 0){
      #pragma unroll 4
      for (int kk = 0; kk < 23; ++kk) TITER(kk)
    } else {
      #pragma unroll 3
      for (int kk = 23; kk < 32; ++kk) TITER(kk)
      const __bf16* __restrict__ Xh = p.Xhi + ((size_t)t*B_ + arow)*KX_ + koffl;
      const __bf16* __restrict__ Xl = p.Xlo + ((size_t)t*B_ + arow)*KX_ + koffl;
      #pragma unroll 4
      for (int kk = 0; kk < 13; ++kk){
        bf16x8 ah = *(const bf16x8*)(Xh + (kk<<5));
        bf16x8 al = *(const bf16x8*)(Xl + (kk<<5));
        bf16x8 q0 = *(const bf16x8*)(Wr0 + H_ + (kk<<5));
        bf16x8 q1 = *(const bf16x8*)(Wr1 + H_ + (kk<<5));
        bf16x8 q2 = *(const bf16x8*)(Wr2 + H_ + (kk<<5));
        bf16x8 q3 = *(const bf16x8*)(Wr3 + H_ + (kk<<5));
        acc0 = MF(ah,q0,acc0); acc0 = MF(al,q0,acc0);
        acc1 = MF(ah,q1,acc1); acc1 = MF(al,q1,acc1);
        acc2 = MF(ah,q2,acc2); acc2 = MF(al,q2,acc2);
        acc3 = MF(ah,q3,acc3); acc3 = MF(al,q3,acc3);
      }
    }
#undef TITER

    if (kh == 1){
      sred[wm][0][l] = acc0; sred[wm][1][l] = acc1;
      sred[wm][2][l] = acc2; sred[wm][3][l] = acc3;
    }
    __syncthreads();
    if (kh == 0){
      acc0 += sred[wm][0][l]; acc1 += sred[wm][1][l];
      acc2 += sred[wm][2][l]; acc3 += sred[wm][3][l];
      float* __restrict__ hout = cell ? p.hR : p.hF;
      const int hcol = h0 + l15;
      #pragma unroll
      for (int q = 0; q < 4; ++q){
        float gi = acc0[q], gf = acc1[q], gg = acc2[q], go = acc3[q];
        float c2 = sigm(gf)*cr4[q] + sigm(gi)*tanhf(gg);
        float h2 = sigm(go)*tanhf(c2);
        cr4[q] = c2;
        int b = (wm<<4) + (lg<<2) + q;
        hout[b*H_ + hcol] = h2;
      }
    }

    bar_t += NBLK_; gbar(p.cnt, bar_t);

    // ================= phase B: attention + binding (blocks 0..63, one batch each) ===
    if (blk < B_){
      const int b = blk;
      for (int i = tid; i < H_; i += NTHR_){ shF[i] = p.hF[b*H_ + i]; shR[i] = p.hR[b*H_ + i]; }
      __syncthreads();

      for (int i = 0; i < 25; ++i){
        int c = (i<<3) + w;                     // 0..199
        const __bf16* __restrict__ wr = p.Wa16 + (size_t)c*H_;
        const float*  hh = (c < NS_) ? shF : shR;
        float s = 0.f;
        #pragma unroll
        for (int m = 0; m < 4; ++m){
          f32x4  hv = *(const f32x4*)&hh[(m<<8) + (l<<2)];
          bf16x4 wv = *(const bf16x4*)(wr + (m<<8) + (l<<2));
          s += hv[0]*(float)wv[0] + hv[1]*(float)wv[1] + hv[2]*(float)wv[2] + hv[3]*(float)wv[3];
        }
        s += __shfl_xor(s,32); s += __shfl_xor(s,16); s += __shfl_xor(s,8);
        s += __shfl_xor(s,4);  s += __shfl_xor(s,2);  s += __shfl_xor(s,1);
        if (l == 0) ssc[c] = s + (c < NS_ ? p.WaFb[c] : p.WaRb[c-NS_]);
      }
      __syncthreads();

      if (w == 0){            // softmax over 150
        float v0 = ssc[l], v1 = ssc[l+64], v2 = (l < 22) ? ssc[l+128] : -3.0e38f;
        float m = fmaxf(fmaxf(v0,v1),v2);
        m = fmaxf(m,__shfl_xor(m,32)); m = fmaxf(m,__shfl_xor(m,16)); m = fmaxf(m,__shfl_xor(m,8));
        m = fmaxf(m,__shfl_xor(m,4));  m = fmaxf(m,__shfl_xor(m,2));  m = fmaxf(m,__shfl_xor(m,1));
        float e0 = expf(v0-m), e1 = expf(v1-m), e2 = (l<22) ? expf(v2-m) : 0.f;
        float s = e0+e1+e2;
        s += __shfl_xor(s,32); s += __shfl_xor(s,16); s += __shfl_xor(s,8);
        s += __shfl_xor(s,4);  s += __shfl_xor(s,2);  s += __shfl_xor(s,1);
        float inv = 1.f/s;
        sa[l] = e0*inv; sa[l+64] = e1*inv; if (l < 22) sa[l+128] = e2*inv;
      } else if (w == 1){     // softmax over 50
        float v = (l < NR_) ? ssc[NS_+l] : -3.0e38f;
        float m = v;
        m = fmaxf(m,__shfl_xor(m,32)); m = fmaxf(m,__shfl_xor(m,16)); m = fmaxf(m,__shfl_xor(m,8));
        m = fmaxf(m,__shfl_xor(m,4));  m = fmaxf(m,__shfl_xor(m,2));  m = fmaxf(m,__shfl_xor(m,1));
        float e = (l < NR_) ? expf(v-m) : 0.f;
        float s = e;
        s += __shfl_xor(s,32); s += __shfl_xor(s,16); s += __shfl_xor(s,8);
        s += __shfl_xor(s,4);  s += __shfl_xor(s,2);  s += __shfl_xor(s,1);
        float inv = 1.f/s;
        if (l < NR_) sa[NS_+l] = e*inv;
      }
      __syncthreads();

      if (tid < 128){
        int d = tid >> 2, part = tid & 3;
        int c0 = part*38, c1 = (c0+38 < NS_) ? c0+38 : NS_;
        float a2 = 0.f;
        for (int c = c0; c < c1; ++c) a2 += sa[c]*p.Fw[d*NS_ + c];
        sitp[tid] = a2;
      } else if (tid < 256){
        int d = (tid-128) >> 2, part = tid & 3;
        int c0 = part*13, c1 = (c0+13 < NR_) ? c0+13 : NR_;
        float a2 = 0.f;
        for (int c = c0; c < c1; ++c) a2 += sa[NS_+c]*p.Rw[d*NR_ + c];
        sitp[tid] = a2;
      }
      __syncthreads();
      if (tid < 32) sit[tid] = p.Fb[tid] + sitp[4*tid]+sitp[4*tid+1]+sitp[4*tid+2]+sitp[4*tid+3];
      else if (tid < 64){ int d = tid-32; sit[tid] = p.Rb[d] + sitp[128+4*d]+sitp[128+4*d+1]+sitp[128+4*d+2]+sitp[128+4*d+3]; }
      __syncthreads();

      const size_t ot = (size_t)b*S_ + t;
      float* __restrict__ outp = p.out + ot*H_;
      for (int e = tid; e < H_; e += NTHR_){
        float v = sit[e>>5]*sit[32 + (e&31)];
        outp[e] = v;
        __bf16 hi = (__bf16)v;
        p.Thi[b*H_ + e] = hi;
        p.Tlo[b*H_ + e] = (__bf16)(v - (float)hi);
      }
      if (tid < NS_)            p.aFo[ot*NS_ + tid]        = sa[tid];
      else if (tid < NS_+NR_)   p.aRo[ot*NR_ + (tid-NS_)]  = sa[tid];
    }

    bar_t += NBLK_; gbar(p.cnt, bar_t);
  }
}

// ---------------- host launch ----------------
extern "C" void kernel_launch(void* const* d_in, const int* in_sizes, int n_in,
                              void* d_out, int out_size, void* d_ws, size_t ws_size,
                              hipStream_t stream){
  const float* x    = (const float*)d_in[0];
  const float* WihF = (const float*)d_in[1];
  const float* WhhF = (const float*)d_in[2];
  const float* bihF = (const float*)d_in[3];
  const float* bhhF = (const float*)d_in[4];
  const float* WihR = (const float*)d_in[5];
  const float* WhhR = (const float*)d_in[6];
  const float* bihR = (const float*)d_in[7];
  const float* bhhR = (const float*)d_in[8];
  const float* WaFw = (const float*)d_in[9];
  const float* WaFb = (const float*)d_in[10];
  const float* WaRw = (const float*)d_in[11];
  const float* WaRb = (const float*)d_in[12];
  const float* Fw   = (const float*)d_in[13];
  const float* Fb   = (const float*)d_in[14];
  const float* Rw   = (const float*)d_in[15];
  const float* Rb   = (const float*)d_in[16];

  char* ws = (char*)d_ws;
  size_t off = 0;
  auto carve = [&](size_t bytes)->void*{ void* p = ws + off; off += (bytes + 255) & ~(size_t)255; return p; };

  __bf16* Wc   = (__bf16*)carve((size_t)2*G4_*KTOT_*2);
  __bf16* Xhi  = (__bf16*)carve((size_t)S_*B_*KX_*2);
  __bf16* Xlo  = (__bf16*)carve((size_t)S_*B_*KX_*2);
  __bf16* Wa16 = (__bf16*)carve((size_t)(NS_+NR_)*H_*2);
  float*  bias = (float*) carve((size_t)2*G4_*4);
  __bf16* Thi  = (__bf16*)carve((size_t)B_*H_*2);
  __bf16* Tlo  = (__bf16*)carve((size_t)B_*H_*2);
  float*  hF   = (float*) carve((size_t)B_*H_*4);
  float*  hR   = (float*) carve((size_t)B_*H_*4);
  unsigned* cnt= (unsigned*)carve(256);
  if (off > ws_size) return;   // workspace too small: bail cleanly

  float* outp = (float*)d_out;
  float* aFo  = outp + (size_t)B_*S_*H_;
  float* aRo  = aFo  + (size_t)B_*S_*NS_;

  prepW<<<2*G4_ + (NS_+NR_), 256, 0, stream>>>(WihF, WhhF, bihF, bhhF, WihR, WhhR, bihR, bhhR,
                                               WaFw, WaRw, Wc, bias, Wa16);
  prepX<<<S_*B_, 64, 0, stream>>>(x, Xhi, Xlo);
  prepZ<<<256, 256, 0, stream>>>((unsigned*)Thi, (unsigned*)Tlo, cnt);

  Params P;
  P.WaFb = WaFb; P.WaRb = WaRb; P.Fw = Fw; P.Fb = Fb; P.Rw = Rw; P.Rb = Rb;
  P.Wc = Wc; P.bias = bias; P.Xhi = Xhi; P.Xlo = Xlo; P.Wa16 = Wa16;
  P.Thi = Thi; P.Tlo = Tlo; P.hF = hF; P.hR = hR;
  P.out = outp; P.aFo = aFo; P.aRo = aRo; P.cnt = cnt;

  tpr_main<<<NBLK_, NTHR_, 0, stream>>>(P);
}

// Round 4
// 10729.437 us; speedup vs baseline: 1.3937x; 1.3937x over previous
//
#include <hip/hip_runtime.h>
#include <hip/hip_bf16.h>

// ---------------- problem constants ----------------
#define B_    64
#define S_    256
#define IN_   400
#define H_    1024
#define G4_   4096
#define NS_   150
#define NR_   50
#define KX_   416           // IN padded to mult of 32
#define KTOT_ 1440          // H + KX
#define NBLK_ 256
#define NTHR_ 256
#define NCHUNK_ 128         // h-chunks per cell (8 cols each)
#define PSF_  152           // partial row stride (F)
#define PSR_  52            // partial row stride (R)
#define LWST_ 1448          // LDS weight row stride in elems (pad vs 1440 for banks)

typedef __attribute__((ext_vector_type(4))) float  f32x4;
typedef __attribute__((ext_vector_type(8))) __bf16 bf16x8;

#define MF(a,b,c) __builtin_amdgcn_mfma_f32_16x16x32_bf16((a),(b),(c),0,0,0)

struct Params {
  const float* WaFw; const float* WaRw; const float* WaFb; const float* WaRb;
  const float* Fw; const float* Fb; const float* Rw; const float* Rb;
  const __bf16* Wc;     // [2][4096][1440] bf16
  const float*  bias;   // [2][4096] (bih+bhh)
  const __bf16* Xhi;    // [256][64][416]
  const __bf16* Xlo;
  float* pbufF;         // [64][128][PSF_]
  float* pbufR;         // [64][128][PSR_]
  float* itbuf;         // [64][64]  (itemF 0..31 | itemR 32..63)
  unsigned* flags;      // 256 flags, stride 16 u32 (64B lines)
  float* out; float* aFo; float* aRo;
};

__device__ __forceinline__ float sigm(float v){ return 1.f/(1.f+expf(-v)); }

// Wave0-only: wait until all 256 block flags >= tgt. Per-lane: 4 flags.
// Bounded (~1ms) so a co-residency failure yields wrong data, not a hang.
__device__ __forceinline__ void poll_flags(const unsigned* flags, unsigned tgt){
  const int l = threadIdx.x & 63;
  unsigned long long t0 = __builtin_amdgcn_s_memrealtime();
  for(;;){
    unsigned a = __hip_atomic_load(flags + ((      l)<<4), __ATOMIC_RELAXED, __HIP_MEMORY_SCOPE_AGENT);
    unsigned b = __hip_atomic_load(flags + (( 64 + l)<<4), __ATOMIC_RELAXED, __HIP_MEMORY_SCOPE_AGENT);
    unsigned c = __hip_atomic_load(flags + ((128 + l)<<4), __ATOMIC_RELAXED, __HIP_MEMORY_SCOPE_AGENT);
    unsigned d = __hip_atomic_load(flags + ((192 + l)<<4), __ATOMIC_RELAXED, __HIP_MEMORY_SCOPE_AGENT);
    bool ok = (a>=tgt) && (b>=tgt) && (c>=tgt) && (d>=tgt);
    if (__all(ok)) break;
    if (__builtin_amdgcn_s_memrealtime() - t0 > 100000ull) break;
    __builtin_amdgcn_s_sleep(4);
  }
}

// ---------------- prep kernels ----------------
__global__ void prepW(const float* __restrict__ WihF, const float* __restrict__ WhhF,
                      const float* __restrict__ bihF, const float* __restrict__ bhhF,
                      const float* __restrict__ WihR, const float* __restrict__ WhhR,
                      const float* __restrict__ bihR, const float* __restrict__ bhhR,
                      __bf16* __restrict__ Wc, float* __restrict__ bias){
  const int row = blockIdx.x;              // 0..8191
  const int cell = row >> 12, n = row & 4095;
  const float* Wih = cell ? WihR : WihF;
  const float* Whh = cell ? WhhR : WhhF;
  __bf16* dst = Wc + (size_t)row * KTOT_;
  for (int k = threadIdx.x; k < KTOT_; k += 256){
    float v;
    if (k < H_)            v = Whh[(size_t)n*H_ + k];
    else if (k < H_+IN_)   v = Wih[(size_t)n*IN_ + (k - H_)];
    else                   v = 0.f;
    dst[k] = (__bf16)v;
  }
  if (threadIdx.x == 0){
    const float* bi = cell ? bihR : bihF;
    const float* bh = cell ? bhhR : bhhF;
    bias[row] = bi[n] + bh[n];
  }
}

__global__ void prepX(const float* __restrict__ x, __bf16* __restrict__ Xhi, __bf16* __restrict__ Xlo){
  const int bi = blockIdx.x;            // t*64 + b
  const int t = bi >> 6, b = bi & 63;
  const float* xr = x + ((size_t)b*S_ + t)*IN_;
  __bf16* dh = Xhi + (size_t)bi*KX_;
  __bf16* dl = Xlo + (size_t)bi*KX_;
  for (int j = threadIdx.x; j < KX_; j += 64){
    float v = (j < IN_) ? xr[j] : 0.f;
    __bf16 h = (__bf16)v;
    dh[j] = h;
    dl[j] = (__bf16)(v - (float)h);
  }
}

__global__ void prepZ(unsigned* __restrict__ flags, float* __restrict__ itbuf){
  int i = blockIdx.x*256 + threadIdx.x;
  if (i < 4096){ flags[i] = 0u; itbuf[i] = 0.f; }
}

// ---------------- main persistent kernel ----------------
// 256 blocks (1/CU) x 256 threads (4 waves). Block = (cell, 8 h-cols).
// Weights LDS-resident. T reconstructed from items (rank-1). 2 flag barriers/step.
__global__ __launch_bounds__(NTHR_) void tpr_main(Params p){
  const int tid = threadIdx.x;
  const int blk = blockIdx.x;
  const int w   = tid >> 6;          // wave 0..3 = m-tile (16 batches)
  const int l   = tid & 63;
  const int l15 = l & 15;
  const int lg  = l >> 4;
  const int cell  = blk >> 7;        // 0=F 1=R
  const int chunk = blk & 127;
  const int h0    = chunk << 3;
  const int col8  = l15 & 7;

  // LDS (static, 143936 B total)
  __shared__ __bf16 lw[32*LWST_];      // weight slice [pair*16+n][K]
  __shared__ float  itL[64*65];        // items [b][0..31 F | 32..63 R], pad 65
  __shared__ float  hb [64*9];         // h2 [b][col8]
  __shared__ float  WaS[152*8];        // Wa slice f32 [c][j]
  __shared__ float  FwS[32*150];
  __shared__ float  RwS[32*50];
  __shared__ float  ssc[200];
  __shared__ float  sa [200];
  __shared__ float  sit[64];

  const int NC = cell ? NR_ : NS_;

  // ---- startup: stage weight slice + Wa slice + Fw/Rw into LDS ----
  for (int idx = tid; idx < 32*180; idx += NTHR_){
    int row = idx/180, ch = idx - (idx/180)*180;
    int g = ((row>>4)<<1) + ((row>>3)&1);      // pair*2 + (n>=8)
    int colc = h0 + (row&7);
    const __bf16* src = p.Wc + ((size_t)(cell*G4_ + g*H_ + colc))*KTOT_ + ch*8;
    *(bf16x8*)(lw + row*LWST_ + ch*8) = *(const bf16x8*)src;
  }
  {
    const float* Waw = cell ? p.WaRw : p.WaFw;
    for (int idx = tid; idx < NC*8; idx += NTHR_){
      int c = idx>>3, j = idx&7;
      WaS[c*8+j] = Waw[(size_t)c*H_ + h0 + j];
    }
    for (int i = tid; i < 32*150; i += NTHR_) FwS[i] = p.Fw[i];
    for (int i = tid; i < 32*50;  i += NTHR_) RwS[i] = p.Rw[i];
  }
  // biases for this lane's column (valid for l15<8)
  const int colc = h0 + col8;
  const float bi_ = p.bias[cell*G4_ + 0*H_ + colc];
  const float bf_ = p.bias[cell*G4_ + 1*H_ + colc];
  const float bg_ = p.bias[cell*G4_ + 2*H_ + colc];
  const float bo_ = p.bias[cell*G4_ + 3*H_ + colc];

  const int arow  = (w<<4) + l15;      // batch row this lane feeds (A operand)
  const int koffl = lg << 3;           // k offset within 32-tile

  float cr4[4] = {0.f,0.f,0.f,0.f};    // c-state (lanes l15<8), persistent
  const f32x4 zero4 = {0.f,0.f,0.f,0.f};

  for (int t = 0; t < S_; ++t){
    // ================= epoch A =================
    if (t > 0){
      if (w == 0){ poll_flags(p.flags, 2u*(unsigned)t); __threadfence(); }
      __syncthreads();
      for (int i = tid; i < 64*64; i += NTHR_) itL[(i>>6)*65 + (i&63)] = p.itbuf[i];
    }
    __syncthreads();

    f32x4 aif = zero4, ago = zero4;    // pair(i,f) / pair(g,o) accumulators

    if (t > 0){                        // T-part: A built from items (rank-1)
      float r8[8];
      #pragma unroll
      for (int j = 0; j < 8; ++j) r8[j] = itL[arow*65 + 32 + koffl + j];
      #pragma unroll 8
      for (int kk = 0; kk < 32; ++kk){
        float s = itL[arow*65 + kk];
        bf16x8 ah;
        #pragma unroll
        for (int j = 0; j < 8; ++j) ah[j] = (__bf16)(s * r8[j]);
        bf16x8 q0 = *(const bf16x8*)(lw + (     l15)*LWST_ + kk*32 + koffl);
        bf16x8 q1 = *(const bf16x8*)(lw + (16 + l15)*LWST_ + kk*32 + koffl);
        aif = MF(ah, q0, aif);
        ago = MF(ah, q1, ago);
      }
    }
    {                                  // X-part (hi+lo split precision)
      const __bf16* Xh = p.Xhi + ((size_t)t*B_ + arow)*KX_ + koffl;
      const __bf16* Xl = p.Xlo + ((size_t)t*B_ + arow)*KX_ + koffl;
      #pragma unroll 4
      for (int kk = 0; kk < 13; ++kk){
        bf16x8 ah = *(const bf16x8*)(Xh + kk*32);
        bf16x8 al = *(const bf16x8*)(Xl + kk*32);
        bf16x8 q0 = *(const bf16x8*)(lw + (     l15)*LWST_ + H_ + kk*32 + koffl);
        bf16x8 q1 = *(const bf16x8*)(lw + (16 + l15)*LWST_ + H_ + kk*32 + koffl);
        aif = MF(ah,q0,aif); aif = MF(al,q0,aif);
        ago = MF(ah,q1,ago); ago = MF(al,q1,ago);
      }
    }
    // fused LSTM pointwise: lane l15 holds i(or f) in aif, g(or o) in ago
    #pragma unroll
    for (int q = 0; q < 4; ++q){
      float v0 = aif[q], v1 = ago[q];
      float fx = __shfl_xor(v0, 8);    // low lanes receive f
      float ox = __shfl_xor(v1, 8);    // low lanes receive o
      if (l15 < 8){
        float i_ = sigm(v0 + bi_), f_ = sigm(fx + bf_);
        float g_ = tanhf(v1 + bg_), o_ = sigm(ox + bo_);
        float c2 = f_*cr4[q] + i_*g_;
        float h2 = o_*tanhf(c2);
        cr4[q] = c2;
        int b = (w<<4) + (lg<<2) + q;
        hb[b*9 + col8] = h2;
      }
    }
    __syncthreads();
    // partial attention scores (8-dim, f32) -> global
    if (cell == 0){
      for (int idx = tid; idx < 64*NS_; idx += NTHR_){
        int b = idx / NS_, c = idx - b*NS_;
        const float* hrow = hb + b*9; const float* wrow = WaS + c*8;
        float sacc = 0.f;
        #pragma unroll
        for (int j = 0; j < 8; ++j) sacc += hrow[j]*wrow[j];
        p.pbufF[((size_t)b*NCHUNK_ + chunk)*PSF_ + c] = sacc;
      }
    } else {
      for (int idx = tid; idx < 64*NR_; idx += NTHR_){
        int b = idx / NR_, c = idx - b*NR_;
        const float* hrow = hb + b*9; const float* wrow = WaS + c*8;
        float sacc = 0.f;
        #pragma unroll
        for (int j = 0; j < 8; ++j) sacc += hrow[j]*wrow[j];
        p.pbufR[((size_t)b*NCHUNK_ + chunk)*PSR_ + c] = sacc;
      }
    }
    __syncthreads();   // drains each wave's stores (vmcnt 0) before signaling
    if (tid == 0){
      __threadfence();  // writeback L2 -> visible device-wide
      __hip_atomic_store(&p.flags[blk<<4], 2u*t+1u, __ATOMIC_RELAXED, __HIP_MEMORY_SCOPE_AGENT);
    }

    // ================= epoch B (blocks 0..63: one batch each) =================
    if (blk < B_){
      const int b = blk;
      if (w == 0){ poll_flags(p.flags, 2u*t+1u); __threadfence(); }
      __syncthreads();
      // reduce partials over 128 chunks
      if (tid < NS_){
        const float* src = p.pbufF + ((size_t)b*NCHUNK_)*PSF_ + tid;
        float s = 0.f;
        #pragma unroll 8
        for (int ch = 0; ch < NCHUNK_; ++ch) s += src[(size_t)ch*PSF_];
        ssc[tid] = s + p.WaFb[tid];
      } else if (tid >= 160 && tid < 160+NR_){
        int c = tid - 160;
        const float* src = p.pbufR + ((size_t)b*NCHUNK_)*PSR_ + c;
        float s = 0.f;
        #pragma unroll 8
        for (int ch = 0; ch < NCHUNK_; ++ch) s += src[(size_t)ch*PSR_];
        ssc[NS_+c] = s + p.WaRb[c];
      }
      __syncthreads();
      if (w == 0){            // softmax over 150
        float v0 = ssc[l], v1 = ssc[l+64], v2 = (l < 22) ? ssc[l+128] : -3.0e38f;
        float m = fmaxf(fmaxf(v0,v1),v2);
        m = fmaxf(m,__shfl_xor(m,32)); m = fmaxf(m,__shfl_xor(m,16)); m = fmaxf(m,__shfl_xor(m,8));
        m = fmaxf(m,__shfl_xor(m,4));  m = fmaxf(m,__shfl_xor(m,2));  m = fmaxf(m,__shfl_xor(m,1));
        float e0 = expf(v0-m), e1 = expf(v1-m), e2 = (l<22) ? expf(v2-m) : 0.f;
        float s = e0+e1+e2;
        s += __shfl_xor(s,32); s += __shfl_xor(s,16); s += __shfl_xor(s,8);
        s += __shfl_xor(s,4);  s += __shfl_xor(s,2);  s += __shfl_xor(s,1);
        float inv = 1.f/s;
        sa[l] = e0*inv; sa[l+64] = e1*inv; if (l < 22) sa[l+128] = e2*inv;
      } else if (w == 1){     // softmax over 50
        float v = (l < NR_) ? ssc[NS_+l] : -3.0e38f;
        float m = v;
        m = fmaxf(m,__shfl_xor(m,32)); m = fmaxf(m,__shfl_xor(m,16)); m = fmaxf(m,__shfl_xor(m,8));
        m = fmaxf(m,__shfl_xor(m,4));  m = fmaxf(m,__shfl_xor(m,2));  m = fmaxf(m,__shfl_xor(m,1));
        float e = (l < NR_) ? expf(v-m) : 0.f;
        float s = e;
        s += __shfl_xor(s,32); s += __shfl_xor(s,16); s += __shfl_xor(s,8);
        s += __shfl_xor(s,4);  s += __shfl_xor(s,2);  s += __shfl_xor(s,1);
        float inv = 1.f/s;
        if (l < NR_) sa[NS_+l] = e*inv;
      }
      __syncthreads();
      if (tid < 32){
        float s = p.Fb[tid];
        for (int c = 0; c < NS_; ++c) s += sa[c]*FwS[tid*NS_+c];
        sit[tid] = s;
      } else if (tid < 64){
        int d = tid - 32;
        float s = p.Rb[d];
        for (int c = 0; c < NR_; ++c) s += sa[NS_+c]*RwS[d*NR_+c];
        sit[32+d] = s;
      }
      __syncthreads();
      const size_t ot = (size_t)b*S_ + t;
      float* op = p.out + ot*H_;
      for (int e = tid; e < H_; e += NTHR_) op[e] = sit[e>>5]*sit[32+(e&31)];
      if (tid < 64) p.itbuf[b*64 + tid] = sit[tid];
      if (tid < NS_)          p.aFo[ot*NS_ + tid]       = sa[tid];
      else if (tid < NS_+NR_) p.aRo[ot*NR_ + (tid-NS_)] = sa[tid];
      __syncthreads();
      if (tid == 0){
        __threadfence();
        __hip_atomic_store(&p.flags[blk<<4], 2u*t+2u, __ATOMIC_RELAXED, __HIP_MEMORY_SCOPE_AGENT);
      }
    } else {
      // nothing written in epoch B: arrive immediately (same-address relaxed stores stay ordered)
      if (tid == 0)
        __hip_atomic_store(&p.flags[blk<<4], 2u*t+2u, __ATOMIC_RELAXED, __HIP_MEMORY_SCOPE_AGENT);
    }
  }
}

// ---------------- host launch ----------------
extern "C" void kernel_launch(void* const* d_in, const int* in_sizes, int n_in,
                              void* d_out, int out_size, void* d_ws, size_t ws_size,
                              hipStream_t stream){
  const float* x    = (const float*)d_in[0];
  const float* WihF = (const float*)d_in[1];
  const float* WhhF = (const float*)d_in[2];
  const float* bihF = (const float*)d_in[3];
  const float* bhhF = (const float*)d_in[4];
  const float* WihR = (const float*)d_in[5];
  const float* WhhR = (const float*)d_in[6];
  const float* bihR = (const float*)d_in[7];
  const float* bhhR = (const float*)d_in[8];
  const float* WaFw = (const float*)d_in[9];
  const float* WaFb = (const float*)d_in[10];
  const float* WaRw = (const float*)d_in[11];
  const float* WaRb = (const float*)d_in[12];
  const float* Fw   = (const float*)d_in[13];
  const float* Fb   = (const float*)d_in[14];
  const float* Rw   = (const float*)d_in[15];
  const float* Rb   = (const float*)d_in[16];

  char* ws = (char*)d_ws;
  size_t off = 0;
  auto carve = [&](size_t bytes)->void*{ void* q = ws + off; off += (bytes + 255) & ~(size_t)255; return q; };

  __bf16* Wc    = (__bf16*)carve((size_t)2*G4_*KTOT_*2);
  __bf16* Xhi   = (__bf16*)carve((size_t)S_*B_*KX_*2);
  __bf16* Xlo   = (__bf16*)carve((size_t)S_*B_*KX_*2);
  float*  bias  = (float*) carve((size_t)2*G4_*4);
  float*  pbufF = (float*) carve((size_t)B_*NCHUNK_*PSF_*4);
  float*  pbufR = (float*) carve((size_t)B_*NCHUNK_*PSR_*4);
  float*  itbuf = (float*) carve((size_t)B_*64*4);
  unsigned* flags = (unsigned*)carve((size_t)4096*4);
  if (off > ws_size) return;   // workspace too small: bail cleanly

  float* outp = (float*)d_out;
  float* aFo  = outp + (size_t)B_*S_*H_;
  float* aRo  = aFo  + (size_t)B_*S_*NS_;

  prepW<<<2*G4_, 256, 0, stream>>>(WihF, WhhF, bihF, bhhF, WihR, WhhR, bihR, bhhR, Wc, bias);
  prepX<<<S_*B_, 64, 0, stream>>>(x, Xhi, Xlo);
  prepZ<<<16, 256, 0, stream>>>(flags, itbuf);

  Params P;
  P.WaFw = WaFw; P.WaRw = WaRw; P.WaFb = WaFb; P.WaRb = WaRb;
  P.Fw = Fw; P.Fb = Fb; P.Rw = Rw; P.Rb = Rb;
  P.Wc = Wc; P.bias = bias; P.Xhi = Xhi; P.Xlo = Xlo;
  P.pbufF = pbufF; P.pbufR = pbufR; P.itbuf = itbuf; P.flags = flags;
  P.out = outp; P.aFo = aFo; P.aRo = aRo;

  tpr_main<<<NBLK_, NTHR_, 0, stream>>>(P);
}